// Round 1
// baseline (116.207 us; speedup 1.0000x reference)
//
#include <hip/hip_runtime.h>
#include <math.h>
#include <float.h>

#define D 64
#define K 15
#define S 120          // K*(K+1)/2
#define MNUM 100
#define C0 (-58.81206612509905f)   // -0.5 * 64 * log(2*pi)
#define L2E 1.4426950408889634f

static __device__ __forceinline__ float fexp2(float x) {
    return __builtin_amdgcn_exp2f(x);
}

// ws layout (as float*): G0[0..119], G1[128..247], G2[256..375],
// then as int*: iA at float-offset 384, iB at float-offset 512.

__global__ __launch_bounds__(128) void gmm_setup(const float* __restrict__ pi,
                                                 const float* __restrict__ mu,
                                                 float* __restrict__ wsf,
                                                 int* __restrict__ wsi,
                                                 float* __restrict__ out) {
    __shared__ float red[2];
    __shared__ float bcast;
    const int t = threadIdx.x;
    const int wid = t >> 6;

    // ---- softmax(pi) over 120 entries ----
    float p = (t < S) ? pi[t] : -FLT_MAX;
    float mx = p;
    for (int off = 32; off; off >>= 1) mx = fmaxf(mx, __shfl_down(mx, off));
    if ((t & 63) == 0) red[wid] = mx;
    __syncthreads();
    if (t == 0) bcast = fmaxf(red[0], red[1]);
    __syncthreads();
    mx = bcast;
    __syncthreads();

    float e = (t < S) ? __expf(p - mx) : 0.f;
    float se = e;
    for (int off = 32; off; off >>= 1) se += __shfl_down(se, off);
    if ((t & 63) == 0) red[wid] = se;
    __syncthreads();
    if (t == 0) bcast = red[0] + red[1];
    __syncthreads();
    se = bcast;

    if (t < S) {
        float sm = e / se;
        float logpi = logf(sm + 1e-30f);   // matches ref's log(softmax + 1e-30)

        // recover (i, j) for s = t  (upper-tri incl diag, row-major)
        int i = 0, rem = t;
        while (rem >= K - i) { rem -= K - i; ++i; }
        int j = i + rem;

        float aa = 0.f, ab = 0.f, bb = 0.f;
        for (int d = 0; d < D; ++d) {
            float ma = mu[d * K + i];
            float mb = mu[d * K + j];
            aa = fmaf(ma, ma, aa);
            ab = fmaf(ma, mb, ab);
            bb = fmaf(mb, mb, bb);
        }
        // mm(w) = q0 + q1*w + q2*w^2
        float q0 = bb;
        float q1 = 2.f * (ab - bb);
        float q2 = aa - 2.f * ab + bb;

        wsf[t]       = C0 + logpi - 0.5f * q0;  // G0
        wsf[128 + t] = -0.5f * q1;              // G1
        wsf[256 + t] = -0.5f * q2;              // G2
        wsi[t]       = i;                       // A[s]
        wsi[128 + t] = j;                       // B[s]
    }
    if (t == 0) out[0] = -logf((float)MNUM);    // final = mean(lse) - log(M)
}

__global__ __launch_bounds__(256) void gmm_main(const float* __restrict__ z,
                                                const float* __restrict__ mu,
                                                const float* __restrict__ wsf,
                                                const int* __restrict__ wsi,
                                                float* __restrict__ out) {
    __shared__ float zsh[D];
    __shared__ float csh[K];
    __shared__ float U0[S], U1[S], U2[S];
    __shared__ float red[4];
    __shared__ float sZZ, sMb;

    const int t = threadIdx.x;
    const int b = blockIdx.x;
    const int wid = t >> 6;

    // ---- load z_b, compute ||z||^2 (wave 0 covers t<64 exactly) ----
    float zv = 0.f;
    if (t < D) { zv = z[b * D + t]; zsh[t] = zv; }
    if (wid == 0) {
        float zsq = zv * zv;
        for (int off = 32; off; off >>= 1) zsq += __shfl_down(zsq, off);
        if (t == 0) sZZ = zsq;
    }
    __syncthreads();

    // ---- c[k] = z_b . mu[:,k] ----
    if (t < K) {
        float acc = 0.f;
        for (int d = 0; d < D; ++d) acc = fmaf(zsh[d], mu[d * K + t], acc);
        csh[t] = acc;
    }
    __syncthreads();

    // ---- per-s quadratic T0 + T1*w + T2*w^2 and analytic max bound ----
    float bnd = -FLT_MAX;
    if (t < S) {
        float cA = csh[wsi[t]];
        float cB = csh[wsi[128 + t]];
        float T0 = wsf[t]       + cB - 0.5f * sZZ;
        float T1 = wsf[128 + t] + (cA - cB);
        float T2 = wsf[256 + t];
        U0[t] = T0; U1[t] = T1; U2[t] = T2;
        float b1 = fmaf(0.99f, fmaf(0.99f, T2, T1), T0);
        bnd = fmaxf(T0, b1);
        if (T2 < 0.f) {                      // concave: clamped vertex bounds grid max
            float wv = -T1 / (2.f * T2);
            wv = fminf(fmaxf(wv, 0.f), 0.99f);
            bnd = fmaxf(bnd, fmaf(wv, fmaf(wv, T2, T1), T0));
        }
    }
    for (int off = 32; off; off >>= 1) bnd = fmaxf(bnd, __shfl_down(bnd, off));
    if ((t & 63) == 0) red[wid] = bnd;
    __syncthreads();
    if (t == 0) sMb = fmaxf(fmaxf(red[0], red[1]), fmaxf(red[2], red[3]));
    __syncthreads();
    const float Mb = sMb;

    // rescale to base-2 so the hot loop is 2 FMA + v_exp_f32
    if (t < S) {
        U0[t] = (U0[t] - Mb) * L2E;
        U1[t] *= L2E;
        U2[t] *= L2E;
    }
    __syncthreads();

    // ---- single-pass sum of exp: 240 threads x 50 m-values ----
    float sum0 = 0.f, sum1 = 0.f;
    if (t < 240) {
        const int s = t >> 1;
        const float u0 = U0[s], u1 = U1[s], u2 = U2[s];
        float w = (t & 1) ? 0.50f : 0.00f;
        #pragma unroll
        for (int j = 0; j < 50; j += 2) {
            float e0 = fmaf(w, fmaf(w, u2, u1), u0);
            sum0 += fexp2(e0);
            float w1 = w + 0.01f;
            float e1 = fmaf(w1, fmaf(w1, u2, u1), u0);
            sum1 += fexp2(e1);
            w += 0.02f;
        }
    }
    float ssum = sum0 + sum1;
    for (int off = 32; off; off >>= 1) ssum += __shfl_down(ssum, off);
    if ((t & 63) == 0) red[wid] = ssum;
    __syncthreads();
    if (t == 0) {
        float tot = red[0] + red[1] + red[2] + red[3];
        float lse = Mb + logf(tot);
        atomicAdd(out, lse * (1.0f / 4096.0f));
    }
}

extern "C" void kernel_launch(void* const* d_in, const int* in_sizes, int n_in,
                              void* d_out, int out_size, void* d_ws, size_t ws_size,
                              hipStream_t stream) {
    const float* z  = (const float*)d_in[0];   // [4096, 1, 64]
    const float* pi = (const float*)d_in[1];   // [1, 120]
    const float* mu = (const float*)d_in[2];   // [64, 15]
    float* out = (float*)d_out;                // scalar

    float* wsf = (float*)d_ws;
    int*   wsi = (int*)(wsf + 384);

    gmm_setup<<<1, 128, 0, stream>>>(pi, mu, wsf, wsi, out);
    gmm_main<<<4096, 256, 0, stream>>>(z, mu, wsf, wsi, out);
}

// Round 2
// 72.582 us; speedup vs baseline: 1.6010x; 1.6010x over previous
//
#include <hip/hip_runtime.h>
#include <math.h>
#include <float.h>

#define D 64
#define K 15
#define S 120          // K*(K+1)/2
#define MNUM 100
#define C0 (-58.81206612509905f)   // -0.5 * 64 * log(2*pi)
#define L2E 1.4426950408889634f
#define INV_L2E 0.6931471805599453f

static __device__ __forceinline__ float fexp2(float x) {
    return __builtin_amdgcn_exp2f(x);
}

// ws layout (float index): G0[0..119], G1[128..247], G2[256..375],
// int iA at [384..503], int iB at [512..631], lse[b] at [1024..5119].

__global__ __launch_bounds__(128) void gmm_setup(const float* __restrict__ pi,
                                                 const float* __restrict__ mu,
                                                 float* __restrict__ wsf,
                                                 int* __restrict__ wsi) {
    __shared__ float red[2];
    __shared__ float bcast;
    const int t = threadIdx.x;
    const int wid = t >> 6;

    // softmax(pi) over 120 entries
    float p = (t < S) ? pi[t] : -FLT_MAX;
    float mx = p;
    for (int off = 32; off; off >>= 1) mx = fmaxf(mx, __shfl_down(mx, off));
    if ((t & 63) == 0) red[wid] = mx;
    __syncthreads();
    if (t == 0) bcast = fmaxf(red[0], red[1]);
    __syncthreads();
    mx = bcast;
    __syncthreads();

    float e = (t < S) ? __expf(p - mx) : 0.f;
    float se = e;
    for (int off = 32; off; off >>= 1) se += __shfl_down(se, off);
    if ((t & 63) == 0) red[wid] = se;
    __syncthreads();
    if (t == 0) bcast = red[0] + red[1];
    __syncthreads();
    se = bcast;

    if (t < S) {
        float sm = e / se;
        float logpi = logf(sm + 1e-30f);   // matches ref's log(softmax + 1e-30)

        // recover (i, j) for s = t (upper-tri incl diag, row-major)
        int i = 0, rem = t;
        while (rem >= K - i) { rem -= K - i; ++i; }
        int j = i + rem;

        float aa = 0.f, ab = 0.f, bb = 0.f;
        for (int d = 0; d < D; ++d) {
            float ma = mu[d * K + i];
            float mb = mu[d * K + j];
            aa = fmaf(ma, ma, aa);
            ab = fmaf(ma, mb, ab);
            bb = fmaf(mb, mb, bb);
        }
        float q0 = bb;
        float q1 = 2.f * (ab - bb);
        float q2 = aa - 2.f * ab + bb;

        wsf[t]       = C0 + logpi - 0.5f * q0;  // G0
        wsf[128 + t] = -0.5f * q1;              // G1
        wsf[256 + t] = -0.5f * q2;              // G2
        wsi[t]       = i;                       // A[s]
        wsi[128 + t] = j;                       // B[s]
    }
}

// One wave per sample. No atomics; one barrier (z staging).
__global__ __launch_bounds__(256) void gmm_main(const float* __restrict__ z,
                                                const float* __restrict__ mu,
                                                const float* __restrict__ wsf,
                                                const int* __restrict__ wsi,
                                                float* __restrict__ lse) {
    __shared__ float zsh[4][D];
    const int t = threadIdx.x;
    const int lane = t & 63;
    const int wv = t >> 6;
    const int b = (blockIdx.x << 2) + wv;

    // ---- z + ||z||^2 (xor-reduce: every lane gets zz) ----
    float zval = z[b * D + lane];
    zsh[wv][lane] = zval;
    float zz = zval * zval;
    #pragma unroll
    for (int off = 32; off; off >>= 1) zz += __shfl_xor(zz, off);
    __syncthreads();   // make zsh visible across lanes (compiler ordering)

    // ---- c[k] = z_b . mu[:,k]; group g covers 16 d's for k = lane&15 ----
    const int g = lane >> 4;
    const int kk = lane & 15;
    const int kkc = (kk < K) ? kk : (K - 1);   // lane kk==15 duplicates c[14]
    const float* zw = &zsh[wv][g * 16];
    float cpart = 0.f;
    #pragma unroll
    for (int i = 0; i < 16; ++i)
        cpart = fmaf(zw[i], mu[(g * 16 + i) * K + kkc], cpart);
    cpart += __shfl_xor(cpart, 16);
    cpart += __shfl_xor(cpart, 32);
    // now lane l holds c[min(l&15, 14)]; lanes 0..14 hold c[0..14]

    // ---- per-s quadratics: s1 = lane, s2 = lane+64 (valid for lane<56) ----
    const int s1 = lane;
    const int s2 = lane + 64;
    const bool v2 = (s2 < S);
    const int s2c = v2 ? s2 : (S - 1);

    float cA1 = __shfl(cpart, wsi[s1]);
    float cB1 = __shfl(cpart, wsi[128 + s1]);
    float cA2 = __shfl(cpart, wsi[s2c]);
    float cB2 = __shfl(cpart, wsi[128 + s2c]);

    float T01 = wsf[s1] + cB1 - 0.5f * zz;
    float T11 = wsf[128 + s1] + (cA1 - cB1);
    float T21 = wsf[256 + s1];
    float T02 = v2 ? (wsf[s2c] + cB2 - 0.5f * zz) : -1e30f;
    float T12 = wsf[128 + s2c] + (cA2 - cB2);
    float T22 = wsf[256 + s2c];

    // analytic max bound of each quadratic over w in [0, 0.99]
    float bnd = fmaxf(T01, fmaf(0.99f, fmaf(0.99f, T21, T11), T01));
    if (T21 < 0.f) {
        float wv1 = fminf(fmaxf(-T11 / (2.f * T21), 0.f), 0.99f);
        bnd = fmaxf(bnd, fmaf(wv1, fmaf(wv1, T21, T11), T01));
    }
    if (v2) {
        float b2 = fmaxf(T02, fmaf(0.99f, fmaf(0.99f, T22, T12), T02));
        if (T22 < 0.f) {
            float wv2 = fminf(fmaxf(-T12 / (2.f * T22), 0.f), 0.99f);
            b2 = fmaxf(b2, fmaf(wv2, fmaf(wv2, T22, T12), T02));
        }
        bnd = fmaxf(bnd, b2);
    }
    #pragma unroll
    for (int off = 32; off; off >>= 1) bnd = fmaxf(bnd, __shfl_xor(bnd, off));
    const float Mb = bnd;

    // base-2 rescale, all in registers
    const float u01 = (T01 - Mb) * L2E, u11 = T11 * L2E, u21 = T21 * L2E;
    const float u02 = (T02 - Mb) * L2E, u12 = T12 * L2E, u22 = T22 * L2E;
    // (invalid s2: u02 ~ -1.4e30 -> exp2 flushes to 0)

    // ---- hot loop: 100 m-values x 2 s per lane ----
    float sumA = 0.f, sumB = 0.f;
    float w = 0.f;
    #pragma unroll 10
    for (int m = 0; m < 100; ++m) {
        sumA += fexp2(fmaf(w, fmaf(w, u21, u11), u01));
        sumB += fexp2(fmaf(w, fmaf(w, u22, u12), u02));
        w += 0.01f;
    }
    float ssum = sumA + sumB;
    #pragma unroll
    for (int off = 32; off; off >>= 1) ssum += __shfl_xor(ssum, off);

    if (lane == 0)
        lse[b] = Mb + __builtin_amdgcn_logf(ssum) * INV_L2E;
}

__global__ __launch_bounds__(256) void gmm_reduce(const float* __restrict__ lse,
                                                  float* __restrict__ out) {
    __shared__ float red[4];
    const int t = threadIdx.x;
    float s = 0.f;
    #pragma unroll
    for (int i = 0; i < 16; ++i) s += lse[t + i * 256];
    #pragma unroll
    for (int off = 32; off; off >>= 1) s += __shfl_down(s, off);
    if ((t & 63) == 0) red[t >> 6] = s;
    __syncthreads();
    if (t == 0)
        out[0] = (red[0] + red[1] + red[2] + red[3]) * (1.0f / 4096.0f)
                 - logf((float)MNUM);
}

extern "C" void kernel_launch(void* const* d_in, const int* in_sizes, int n_in,
                              void* d_out, int out_size, void* d_ws, size_t ws_size,
                              hipStream_t stream) {
    const float* z  = (const float*)d_in[0];   // [4096, 1, 64]
    const float* pi = (const float*)d_in[1];   // [1, 120]
    const float* mu = (const float*)d_in[2];   // [64, 15]
    float* out = (float*)d_out;                // scalar

    float* wsf = (float*)d_ws;
    int*   wsi = (int*)(wsf + 384);
    float* lse = wsf + 1024;                   // 4096 floats

    gmm_setup<<<1, 128, 0, stream>>>(pi, mu, wsf, wsi);
    gmm_main<<<1024, 256, 0, stream>>>(z, mu, wsf, wsi, lse);
    gmm_reduce<<<1, 256, 0, stream>>>(lse, out);
}

// Round 3
// 69.043 us; speedup vs baseline: 1.6831x; 1.0513x over previous
//
#include <hip/hip_runtime.h>
#include <math.h>
#include <float.h>

#define D 64
#define K 15
#define S 120          // K*(K+1)/2
#define MNUM 100
#define C0 (-58.81206612509905f)   // -0.5 * 64 * log(2*pi)
#define L2E 1.4426950408889634f
#define INV_L2E 0.6931471805599453f

static __device__ __forceinline__ float fexp2(float x) {
    return __builtin_amdgcn_exp2f(x);
}

// ws layout (float index): G0[0..119], G1[128..247], G2[256..375],
// int iA at [384..503], int iB at [512..631], lse[b] at [1024..5119].

__global__ __launch_bounds__(128) void gmm_setup(const float* __restrict__ pi,
                                                 const float* __restrict__ mu,
                                                 float* __restrict__ wsf,
                                                 int* __restrict__ wsi) {
    __shared__ float red[2];
    __shared__ float bcast;
    const int t = threadIdx.x;
    const int wid = t >> 6;

    // softmax(pi) over 120 entries
    float p = (t < S) ? pi[t] : -FLT_MAX;
    float mx = p;
    for (int off = 32; off; off >>= 1) mx = fmaxf(mx, __shfl_down(mx, off));
    if ((t & 63) == 0) red[wid] = mx;
    __syncthreads();
    if (t == 0) bcast = fmaxf(red[0], red[1]);
    __syncthreads();
    mx = bcast;
    __syncthreads();

    float e = (t < S) ? __expf(p - mx) : 0.f;
    float se = e;
    for (int off = 32; off; off >>= 1) se += __shfl_down(se, off);
    if ((t & 63) == 0) red[wid] = se;
    __syncthreads();
    if (t == 0) bcast = red[0] + red[1];
    __syncthreads();
    se = bcast;

    if (t < S) {
        float sm = e / se;
        float logpi = logf(sm + 1e-30f);   // matches ref's log(softmax + 1e-30)

        // recover (i, j) for s = t (upper-tri incl diag, row-major)
        int i = 0, rem = t;
        while (rem >= K - i) { rem -= K - i; ++i; }
        int j = i + rem;

        float aa = 0.f, ab = 0.f, bb = 0.f;
        for (int d = 0; d < D; ++d) {
            float ma = mu[d * K + i];
            float mb = mu[d * K + j];
            aa = fmaf(ma, ma, aa);
            ab = fmaf(ma, mb, ab);
            bb = fmaf(mb, mb, bb);
        }
        float q0 = bb;
        float q1 = 2.f * (ab - bb);
        float q2 = aa - 2.f * ab + bb;

        wsf[t]       = C0 + logpi - 0.5f * q0;  // G0
        wsf[128 + t] = -0.5f * q1;              // G1
        wsf[256 + t] = -0.5f * q2;              // G2  (== -0.5*||muA-muB||^2 <= 0)
        wsi[t]       = i;                       // A[s]
        wsi[128 + t] = j;                       // B[s]
    }
}

// One wave per sample. No atomics; one barrier (z staging).
__global__ __launch_bounds__(256) void gmm_main(const float* __restrict__ z,
                                                const float* __restrict__ mu,
                                                const float* __restrict__ wsf,
                                                const int* __restrict__ wsi,
                                                float* __restrict__ lse) {
    __shared__ float zsh[4][D];
    const int t = threadIdx.x;
    const int lane = t & 63;
    const int wv = t >> 6;
    const int b = (blockIdx.x << 2) + wv;

    // ---- z + ||z||^2 (xor-reduce: every lane gets zz) ----
    float zval = z[b * D + lane];
    zsh[wv][lane] = zval;
    float zz = zval * zval;
    #pragma unroll
    for (int off = 32; off; off >>= 1) zz += __shfl_xor(zz, off);
    __syncthreads();

    // ---- c[k] = z_b . mu[:,k]; group g covers 16 d's for k = lane&15 ----
    const int g = lane >> 4;
    const int kk = lane & 15;
    const int kkc = (kk < K) ? kk : (K - 1);
    const float* zw = &zsh[wv][g * 16];
    float cpart = 0.f;
    #pragma unroll
    for (int i = 0; i < 16; ++i)
        cpart = fmaf(zw[i], mu[(g * 16 + i) * K + kkc], cpart);
    cpart += __shfl_xor(cpart, 16);
    cpart += __shfl_xor(cpart, 32);
    // lanes 0..14 hold c[0..14]

    // ---- per-s quadratics: s1 = lane, s2 = lane+64 (valid for lane<56) ----
    const int s1 = lane;
    const int s2 = lane + 64;
    const bool v2 = (s2 < S);
    const int s2c = v2 ? s2 : (S - 1);

    float cA1 = __shfl(cpart, wsi[s1]);
    float cB1 = __shfl(cpart, wsi[128 + s1]);
    float cA2 = __shfl(cpart, wsi[s2c]);
    float cB2 = __shfl(cpart, wsi[128 + s2c]);

    float T01 = wsf[s1] + cB1 - 0.5f * zz;
    float T11 = wsf[128 + s1] + (cA1 - cB1);
    float T21 = wsf[256 + s1];
    float T02 = v2 ? (wsf[s2c] + cB2 - 0.5f * zz) : -1e30f;
    float T12 = wsf[128 + s2c] + (cA2 - cB2);
    float T22 = wsf[256 + s2c];

    // analytic max bound over w in [0, 0.99] (quadratics are concave: T2 <= 0)
    float bnd = fmaxf(T01, fmaf(0.99f, fmaf(0.99f, T21, T11), T01));
    if (T21 < 0.f) {
        float wv1 = fminf(fmaxf(-T11 * 0.5f * __builtin_amdgcn_rcpf(T21), 0.f), 0.99f);
        bnd = fmaxf(bnd, fmaf(wv1, fmaf(wv1, T21, T11), T01));
    }
    if (v2) {
        float b2 = fmaxf(T02, fmaf(0.99f, fmaf(0.99f, T22, T12), T02));
        if (T22 < 0.f) {
            float wv2 = fminf(fmaxf(-T12 * 0.5f * __builtin_amdgcn_rcpf(T22), 0.f), 0.99f);
            b2 = fmaxf(b2, fmaf(wv2, fmaf(wv2, T22, T12), T02));
        }
        bnd = fmaxf(bnd, b2);
    }
    #pragma unroll
    for (int off = 32; off; off >>= 1) bnd = fmaxf(bnd, __shfl_xor(bnd, off));
    const float Mb = bnd;

    // ---- log2-domain coefficients (a0 includes -Mb) ----
    const float a01 = (T01 - Mb) * L2E, a11 = T11 * L2E, a21 = T21 * L2E;
    const float a02 = (T02 - Mb) * L2E, a12 = T12 * L2E, a22 = T22 * L2E;

    // Multiplicative recurrence, initialized at w=0.5 (m=50), run outward.
    // e_{m+1}/e_m = exp2(a1*d + a2*d^2*(2m+1)), ratio-of-ratios h = exp2(2*a2*d^2).
    // Concavity (a2<=0) => outward decay is monotone past the vertex, so
    // flush-to-zero only loses negligible terms; init at mid is within
    // |a2|/4 log2-units of the peak (no spurious underflow).
    float e1  = fexp2(fmaf(0.5f, fmaf(0.5f, a21, a11), a01));  // e at m=50
    float g1  = fexp2(fmaf(0.0101f, a21,  0.01f * a11));       // e51/e50
    float dd1 = fexp2(fmaf(-0.0099f, a21, -0.01f * a11));      // e49/e50
    float h1  = fexp2(2.0e-4f * a21);

    float e2  = fexp2(fmaf(0.5f, fmaf(0.5f, a22, a12), a02));
    float g2  = fexp2(fmaf(0.0101f, a22,  0.01f * a12));
    float dd2 = fexp2(fmaf(-0.0099f, a22, -0.01f * a12));
    float h2  = fexp2(2.0e-4f * a22);

    float eu1 = e1,        gu1 = g1;
    float ed1 = e1 * dd1,  du1 = dd1 * h1;
    float eu2 = e2,        gu2 = g2;
    float ed2 = e2 * dd2,  du2 = dd2 * h2;
    float su1 = 0.f, sd1 = 0.f, su2 = 0.f, sd2 = 0.f;

    #pragma unroll 10
    for (int m = 0; m < 50; ++m) {
        su1 += eu1; eu1 *= gu1; gu1 *= h1;   // e_50 .. e_99
        sd1 += ed1; ed1 *= du1; du1 *= h1;   // e_49 .. e_0
        su2 += eu2; eu2 *= gu2; gu2 *= h2;
        sd2 += ed2; ed2 *= du2; du2 *= h2;
    }

    float ssum = (su1 + sd1) + (su2 + sd2);
    #pragma unroll
    for (int off = 32; off; off >>= 1) ssum += __shfl_xor(ssum, off);

    if (lane == 0)
        lse[b] = Mb + __builtin_amdgcn_logf(ssum) * INV_L2E;
}

__global__ __launch_bounds__(256) void gmm_reduce(const float* __restrict__ lse,
                                                  float* __restrict__ out) {
    __shared__ float red[4];
    const int t = threadIdx.x;
    float s = 0.f;
    #pragma unroll
    for (int i = 0; i < 16; ++i) s += lse[t + i * 256];
    #pragma unroll
    for (int off = 32; off; off >>= 1) s += __shfl_down(s, off);
    if ((t & 63) == 0) red[t >> 6] = s;
    __syncthreads();
    if (t == 0)
        out[0] = (red[0] + red[1] + red[2] + red[3]) * (1.0f / 4096.0f)
                 - logf((float)MNUM);
}

extern "C" void kernel_launch(void* const* d_in, const int* in_sizes, int n_in,
                              void* d_out, int out_size, void* d_ws, size_t ws_size,
                              hipStream_t stream) {
    const float* z  = (const float*)d_in[0];   // [4096, 1, 64]
    const float* pi = (const float*)d_in[1];   // [1, 120]
    const float* mu = (const float*)d_in[2];   // [64, 15]
    float* out = (float*)d_out;                // scalar

    float* wsf = (float*)d_ws;
    int*   wsi = (int*)(wsf + 384);
    float* lse = wsf + 1024;                   // 4096 floats

    gmm_setup<<<1, 128, 0, stream>>>(pi, mu, wsf, wsi);
    gmm_main<<<1024, 256, 0, stream>>>(z, mu, wsf, wsi, lse);
    gmm_reduce<<<1, 256, 0, stream>>>(lse, out);
}